// Round 8
// baseline (325.722 us; speedup 1.0000x reference)
//
#include <hip/hip_runtime.h>
#include <math.h>

#define C_DIM 128
#define KNN 8
#define NPTS 8192
#define M_TOTAL 16384   // B*N
#define CHUNK 1024      // points staged in LDS per iteration of the KNN scan
#define CAND_CAP 64     // per-query candidate buffer (expected use: 8-16)

typedef unsigned long long u64;

// ---------------------------------------------------------------------------
// Kernel 1: coords -> packed float4 {x, y, z, |p|^2} per point
// ---------------------------------------------------------------------------
__global__ __launch_bounds__(256) void prep_coords(
    const float* __restrict__ coords, float4* __restrict__ c4) {
  int g = blockIdx.x * 256 + threadIdx.x;
  if (g < M_TOTAL) {
    float x = coords[3 * g + 0];
    float y = coords[3 * g + 1];
    float z = coords[3 * g + 2];
    // same fma ordering as the scan's dot product so self-distance cancels
    // to exactly 0.0f
    float s = fmaf(x, x, fmaf(y, y, z * z));
    c4[g] = make_float4(x, y, z, s);
  }
}

// ---------------------------------------------------------------------------
// Kernel 2: transpose the four 128x128 weight matrices once: WT[c][o]=W[o][c]
// ---------------------------------------------------------------------------
__global__ __launch_bounds__(256) void transpose_w(
    const float* __restrict__ Wq, const float* __restrict__ Wk,
    const float* __restrict__ Wv, const float* __restrict__ Wo,
    float* __restrict__ Tq, float* __restrict__ Tk,
    float* __restrict__ Tv, float* __restrict__ To) {
  int g = blockIdx.x * 256 + threadIdx.x;
  int mat = g >> 14;          // 0..3
  int j = g & 16383;          // dest linear index: j = c*128 + o
  int c = j >> 7, o = j & 127;
  const float* src = (mat == 0) ? Wq : (mat == 1) ? Wk : (mat == 2) ? Wv : Wo;
  float* dst = (mat == 0) ? Tq : (mat == 1) ? Tk : (mat == 2) ? Tv : To;
  dst[j] = src[o * C_DIM + c];   // coalesced write, strided (L2-hit) read
}

// ---------------------------------------------------------------------------
__device__ __forceinline__ void stage_x64_512(
    float (*Xs)[132], const float* __restrict__ X, int row0, int t) {
  const float4* X4 = (const float4*)(X + (size_t)row0 * C_DIM);
  for (int i = t; i < 64 * 32; i += 512) {
    int r = i >> 5, c4i = i & 31;
    *(float4*)&Xs[r][c4i * 4] = X4[i];
  }
}

// ---------------------------------------------------------------------------
// Kernel 3a: fused q/k/v projection, interleaved in one c-loop.
// 512 threads (8 waves -> 2 waves/SIMD for latency hiding), 64-row tiles,
// 2 rows x 8 cols x 3 matrices per thread. FMA order per output unchanged.
// ---------------------------------------------------------------------------
__global__ __launch_bounds__(512) void gemm_qkv(
    const float* __restrict__ X,
    const float* __restrict__ WTq, const float* __restrict__ WTk,
    const float* __restrict__ WTv,
    float* __restrict__ Yq, float* __restrict__ Yk, float* __restrict__ Yv) {
  __shared__ float Xs[64][132];
  const int t = threadIdx.x;
  const int row0 = blockIdx.x * 64;
  stage_x64_512(Xs, X, row0, t);
  __syncthreads();

  const int r0 = (t >> 4) * 2;   // 32 row-groups x 2 rows
  const int o0 = (t & 15) * 8;   // 16 col-groups x 8 cols

  float aq[2][8], ak[2][8], av[2][8];
#pragma unroll
  for (int i = 0; i < 2; ++i)
#pragma unroll
    for (int j = 0; j < 8; ++j) { aq[i][j] = 0.f; ak[i][j] = 0.f; av[i][j] = 0.f; }

  for (int c = 0; c < C_DIM; c += 4) {
    float xs[2][4];
#pragma unroll
    for (int i = 0; i < 2; ++i) {
      float4 xv = *(const float4*)&Xs[r0 + i][c];
      xs[i][0] = xv.x; xs[i][1] = xv.y; xs[i][2] = xv.z; xs[i][3] = xv.w;
    }
#pragma unroll
    for (int cc = 0; cc < 4; ++cc) {
      const size_t wrow = (size_t)(c + cc) * C_DIM + o0;
      float4 qa = *(const float4*)&WTq[wrow];
      float4 qb = *(const float4*)&WTq[wrow + 4];
      float4 ka = *(const float4*)&WTk[wrow];
      float4 kb = *(const float4*)&WTk[wrow + 4];
      float4 va = *(const float4*)&WTv[wrow];
      float4 vb = *(const float4*)&WTv[wrow + 4];
#pragma unroll
      for (int i = 0; i < 2; ++i) {
        float x = xs[i][cc];
        aq[i][0] = fmaf(x, qa.x, aq[i][0]); aq[i][1] = fmaf(x, qa.y, aq[i][1]);
        aq[i][2] = fmaf(x, qa.z, aq[i][2]); aq[i][3] = fmaf(x, qa.w, aq[i][3]);
        aq[i][4] = fmaf(x, qb.x, aq[i][4]); aq[i][5] = fmaf(x, qb.y, aq[i][5]);
        aq[i][6] = fmaf(x, qb.z, aq[i][6]); aq[i][7] = fmaf(x, qb.w, aq[i][7]);
        ak[i][0] = fmaf(x, ka.x, ak[i][0]); ak[i][1] = fmaf(x, ka.y, ak[i][1]);
        ak[i][2] = fmaf(x, ka.z, ak[i][2]); ak[i][3] = fmaf(x, ka.w, ak[i][3]);
        ak[i][4] = fmaf(x, kb.x, ak[i][4]); ak[i][5] = fmaf(x, kb.y, ak[i][5]);
        ak[i][6] = fmaf(x, kb.z, ak[i][6]); ak[i][7] = fmaf(x, kb.w, ak[i][7]);
        av[i][0] = fmaf(x, va.x, av[i][0]); av[i][1] = fmaf(x, va.y, av[i][1]);
        av[i][2] = fmaf(x, va.z, av[i][2]); av[i][3] = fmaf(x, va.w, av[i][3]);
        av[i][4] = fmaf(x, vb.x, av[i][4]); av[i][5] = fmaf(x, vb.y, av[i][5]);
        av[i][6] = fmaf(x, vb.z, av[i][6]); av[i][7] = fmaf(x, vb.w, av[i][7]);
      }
    }
  }

#pragma unroll
  for (int i = 0; i < 2; ++i) {
    const size_t yoff = (size_t)(row0 + r0 + i) * C_DIM + o0;
    *(float4*)&Yq[yoff] = make_float4(aq[i][0], aq[i][1], aq[i][2], aq[i][3]);
    *(float4*)&Yq[yoff + 4] = make_float4(aq[i][4], aq[i][5], aq[i][6], aq[i][7]);
    *(float4*)&Yk[yoff] = make_float4(ak[i][0], ak[i][1], ak[i][2], ak[i][3]);
    *(float4*)&Yk[yoff + 4] = make_float4(ak[i][4], ak[i][5], ak[i][6], ak[i][7]);
    *(float4*)&Yv[yoff] = make_float4(av[i][0], av[i][1], av[i][2], av[i][3]);
    *(float4*)&Yv[yoff + 4] = make_float4(av[i][4], av[i][5], av[i][6], av[i][7]);
  }
}

// ---------------------------------------------------------------------------
// Kernel 3b: single GEMM (output projection), 512 threads, 64-row tiles.
// ---------------------------------------------------------------------------
__global__ __launch_bounds__(512) void gemm_xwt(
    const float* __restrict__ X, const float* __restrict__ WT,
    float* __restrict__ Y) {
  __shared__ float Xs[64][132];
  const int t = threadIdx.x;
  const int row0 = blockIdx.x * 64;
  stage_x64_512(Xs, X, row0, t);
  __syncthreads();

  const int r0 = (t >> 4) * 2;
  const int o0 = (t & 15) * 8;

  float acc[2][8];
#pragma unroll
  for (int i = 0; i < 2; ++i)
#pragma unroll
    for (int j = 0; j < 8; ++j) acc[i][j] = 0.0f;

  for (int c = 0; c < C_DIM; c += 4) {
    float xs[2][4];
#pragma unroll
    for (int i = 0; i < 2; ++i) {
      float4 xv = *(const float4*)&Xs[r0 + i][c];
      xs[i][0] = xv.x; xs[i][1] = xv.y; xs[i][2] = xv.z; xs[i][3] = xv.w;
    }
#pragma unroll
    for (int cc = 0; cc < 4; ++cc) {
      const size_t wrow = (size_t)(c + cc) * C_DIM + o0;
      float4 wa = *(const float4*)&WT[wrow];
      float4 wb = *(const float4*)&WT[wrow + 4];
#pragma unroll
      for (int i = 0; i < 2; ++i) {
        float x = xs[i][cc];
        acc[i][0] = fmaf(x, wa.x, acc[i][0]); acc[i][1] = fmaf(x, wa.y, acc[i][1]);
        acc[i][2] = fmaf(x, wa.z, acc[i][2]); acc[i][3] = fmaf(x, wa.w, acc[i][3]);
        acc[i][4] = fmaf(x, wb.x, acc[i][4]); acc[i][5] = fmaf(x, wb.y, acc[i][5]);
        acc[i][6] = fmaf(x, wb.z, acc[i][6]); acc[i][7] = fmaf(x, wb.w, acc[i][7]);
      }
    }
  }

#pragma unroll
  for (int i = 0; i < 2; ++i) {
    float* yrow = Y + (size_t)(row0 + r0 + i) * C_DIM + o0;
    *(float4*)yrow = make_float4(acc[i][0], acc[i][1], acc[i][2], acc[i][3]);
    *(float4*)(yrow + 4) = make_float4(acc[i][4], acc[i][5], acc[i][6], acc[i][7]);
  }
}

// ---------------------------------------------------------------------------
// Kernel 4: fused KNN + attention, TWO QUERIES PER WAVE.
// Each ds_read of a point feeds distance math for 2 queries: LDS read
// traffic and staging halve; per-point VALU unchanged; kk0/kk1 chains ILP.
// Pass A: branchless per-lane top-8 of d2 values (min/max bubble).
// tau8: wave-global ~8th smallest (>= s8, safe superset).
// Pass B: ballot-compact (d2,idx) candidates <= tau8; exact lex top-8.
// ---------------------------------------------------------------------------
__device__ __forceinline__ u64 wave_min_u64(u64 x) {
#pragma unroll
  for (int off = 32; off > 0; off >>= 1) {
    u64 o = __shfl_xor(x, off, 64);
    x = (o < x) ? o : x;
  }
  return x;
}

__device__ __forceinline__ void bubble8(float (&kk)[KNN], float e) {
#pragma unroll
  for (int j = 0; j < KNN; ++j) {
    float lo = fminf(kk[j], e);
    float hi = fmaxf(kk[j], e);
    kk[j] = lo;
    e = hi;   // e exits as the dropped (9th) value
  }
}

__device__ __forceinline__ float wave_8th_smallest_f32(const float kk[KNN]) {
  float u[KNN];
#pragma unroll
  for (int j = 0; j < KNN; ++j) u[j] = kk[j];
  float m = 0.0f;
#pragma unroll
  for (int r = 0; r < KNN; ++r) {
    m = u[0];   // per-lane arrays ascending -> u[0] is lane min
#pragma unroll
    for (int off = 32; off > 0; off >>= 1) {
      float o = __shfl_xor(m, off, 64);
      m = fminf(m, o);
    }
    bool mine = (u[0] == m);   // every lane holding m pops one element
#pragma unroll
    for (int j = 0; j < KNN - 1; ++j) u[j] = mine ? u[j + 1] : u[j];
    u[KNN - 1] = mine ? INFINITY : u[KNN - 1];
  }
  return m;
}

__device__ __forceinline__ void attend_one(
    const float4* __restrict__ c4, const float* __restrict__ q,
    const float* __restrict__ k, const float* __restrict__ v,
    float lg, int base, int n, float4 qp, const int (&ni_)[KNN], int lane,
    float* __restrict__ agg) {
  const size_t qrow = (size_t)(base + n) * C_DIM;
  const float qv0 = q[qrow + lane];
  const float qv1 = q[qrow + lane + 64];

  float score[KNN];
#pragma unroll
  for (int j = 0; j < KNN; ++j) {
    const int mj = ni_[j];
    const size_t krow = (size_t)(base + mj) * C_DIM;
    float p = fmaf(qv1, k[krow + lane + 64], qv0 * k[krow + lane]);
#pragma unroll
    for (int off = 32; off > 0; off >>= 1) p += __shfl_xor(p, off, 64);
    // gamma from the diff-based safe norm (reference's second formula)
    const float4 pm = c4[base + mj];
    float dx = qp.x - pm.x, dy = qp.y - pm.y, dz = qp.z - pm.z;
    float d2p = fmaf(dx, dx, fmaf(dy, dy, dz * dz));
    float dist = d2p > 0.0f ? sqrtf(d2p) : 0.0f;
    float gw = expf(lg * dist);
    score[j] = (p / 11.313708498984761f) * gw;   // /sqrt(128) then *gamma
  }

  float mx = score[0];
#pragma unroll
  for (int j = 1; j < KNN; ++j) mx = fmaxf(mx, score[j]);
  float w[KNN]; float sum = 0.0f;
#pragma unroll
  for (int j = 0; j < KNN; ++j) { w[j] = expf(score[j] - mx); sum += w[j]; }
#pragma unroll
  for (int j = 0; j < KNN; ++j) w[j] = w[j] / sum;

  float a0 = 0.0f, a1 = 0.0f;
#pragma unroll
  for (int j = 0; j < KNN; ++j) {
    const size_t vrow = (size_t)(base + ni_[j]) * C_DIM;
    a0 = fmaf(w[j], v[vrow + lane], a0);
    a1 = fmaf(w[j], v[vrow + lane + 64], a1);
  }
  agg[qrow + lane] = a0;
  agg[qrow + lane + 64] = a1;
}

__global__ __launch_bounds__(256) void knn_attn(
    const float4* __restrict__ c4,
    const float* __restrict__ q, const float* __restrict__ k,
    const float* __restrict__ v, const float* __restrict__ log_gamma_p,
    float* __restrict__ agg) {
  __shared__ float4 pts[CHUNK];          // 16 KB
  __shared__ u64 cand[8][CAND_CAP];      // 4 KB, per-query candidate buffers

  const int t = threadIdx.x;
  const int wave = t >> 6;
  const int lane = t & 63;
  const int q0i = blockIdx.x * 8 + wave * 2;     // 8 queries/block; blocks
  const int b = q0i >> 13;                       // never straddle a batch
  const int n0 = q0i & (NPTS - 1);
  const int base = b * NPTS;

  const float4 qp0 = c4[base + n0];
  const float4 qp1 = c4[base + n0 + 1];
  const u64 lmask = (1ull << lane) - 1ull;

  // ---------------- pass A: values-only top-8 x 2 queries ----------------
  float kk0[KNN], kk1[KNN];
#pragma unroll
  for (int j = 0; j < KNN; ++j) { kk0[j] = INFINITY; kk1[j] = INFINITY; }

  for (int ch = 0; ch < NPTS / CHUNK; ++ch) {
    __syncthreads();   // previous chunk fully consumed
    for (int i = t; i < CHUNK; i += 256) pts[i] = c4[base + ch * CHUNK + i];
    __syncthreads();

#pragma unroll
    for (int it = 0; it < CHUNK / 128; ++it) {   // 2 points x 2 queries
      const int ml = it * 128 + lane;
      const float4 pa = pts[ml];
      const float4 pb = pts[ml + 64];
      float dota0 = fmaf(qp0.x, pa.x, fmaf(qp0.y, pa.y, qp0.z * pa.z));
      float dotb0 = fmaf(qp0.x, pb.x, fmaf(qp0.y, pb.y, qp0.z * pb.z));
      float dota1 = fmaf(qp1.x, pa.x, fmaf(qp1.y, pa.y, qp1.z * pa.z));
      float dotb1 = fmaf(qp1.x, pb.x, fmaf(qp1.y, pb.y, qp1.z * pb.z));
      float d2a0 = fmaxf(qp0.w + pa.w - 2.0f * dota0, 0.0f);
      float d2b0 = fmaxf(qp0.w + pb.w - 2.0f * dotb0, 0.0f);
      float d2a1 = fmaxf(qp1.w + pa.w - 2.0f * dota1, 0.0f);
      float d2b1 = fmaxf(qp1.w + pb.w - 2.0f * dotb1, 0.0f);
      bubble8(kk0, d2a0); bubble8(kk1, d2a1);   // two independent chains
      bubble8(kk0, d2b0); bubble8(kk1, d2b1);
    }
  }

  const float tau0 = wave_8th_smallest_f32(kk0);
  const float tau1 = wave_8th_smallest_f32(kk1);

  // ---------------- pass B: collect candidates <= tau ---------------------
  int cnt0 = 0, cnt1 = 0;
  for (int ch = 0; ch < NPTS / CHUNK; ++ch) {
    __syncthreads();
    for (int i = t; i < CHUNK; i += 256) pts[i] = c4[base + ch * CHUNK + i];
    __syncthreads();

#pragma unroll
    for (int it = 0; it < CHUNK / 128; ++it) {
      const int ml = it * 128 + lane;
      const float4 pa = pts[ml];
      const float4 pb = pts[ml + 64];
      float dota0 = fmaf(qp0.x, pa.x, fmaf(qp0.y, pa.y, qp0.z * pa.z));
      float dotb0 = fmaf(qp0.x, pb.x, fmaf(qp0.y, pb.y, qp0.z * pb.z));
      float dota1 = fmaf(qp1.x, pa.x, fmaf(qp1.y, pa.y, qp1.z * pa.z));
      float dotb1 = fmaf(qp1.x, pb.x, fmaf(qp1.y, pb.y, qp1.z * pb.z));
      float d2a0 = fmaxf(qp0.w + pa.w - 2.0f * dota0, 0.0f);
      float d2b0 = fmaxf(qp0.w + pb.w - 2.0f * dotb0, 0.0f);
      float d2a1 = fmaxf(qp1.w + pa.w - 2.0f * dota1, 0.0f);
      float d2b1 = fmaxf(qp1.w + pb.w - 2.0f * dotb1, 0.0f);
      bool ga0 = d2a0 <= tau0, gb0 = d2b0 <= tau0;
      bool ga1 = d2a1 <= tau1, gb1 = d2b1 <= tau1;
      u64 ma0 = __ballot(ga0), mb0 = __ballot(gb0);
      u64 ma1 = __ballot(ga1), mb1 = __ballot(gb1);
      if (ma0 | mb0 | ma1 | mb1) {   // rarely-taken, wave-uniform branch
        const unsigned ia = (unsigned)(ch * CHUNK + ml);
        if (ga0) {
          int pos = cnt0 + (int)__popcll(ma0 & lmask);
          if (pos < CAND_CAP)
            cand[wave * 2][pos] = ((u64)__float_as_uint(d2a0) << 32) | ia;
        }
        cnt0 += (int)__popcll(ma0);
        if (gb0) {
          int pos = cnt0 + (int)__popcll(mb0 & lmask);
          if (pos < CAND_CAP)
            cand[wave * 2][pos] = ((u64)__float_as_uint(d2b0) << 32) | (ia + 64);
        }
        cnt0 += (int)__popcll(mb0);
        if (ga1) {
          int pos = cnt1 + (int)__popcll(ma1 & lmask);
          if (pos < CAND_CAP)
            cand[wave * 2 + 1][pos] = ((u64)__float_as_uint(d2a1) << 32) | ia;
        }
        cnt1 += (int)__popcll(ma1);
        if (gb1) {
          int pos = cnt1 + (int)__popcll(mb1 & lmask);
          if (pos < CAND_CAP)
            cand[wave * 2 + 1][pos] = ((u64)__float_as_uint(d2b1) << 32) | (ia + 64);
        }
        cnt1 += (int)__popcll(mb1);
      }
    }
  }

  // ------------- final exact top-8 per query (lex (d2, idx)) -------------
  int ni0_[KNN], ni1_[KNN];
  {
    const int m0 = (cnt0 < CAND_CAP) ? cnt0 : CAND_CAP;
    u64 my0 = (lane < m0) ? cand[wave * 2][lane] : ~0ull;
#pragma unroll
    for (int r = 0; r < KNN; ++r) {
      u64 mm = wave_min_u64(my0);
      ni0_[r] = (int)(unsigned)(mm & 0xFFFFFFFFu);
      if (my0 == mm) my0 = ~0ull;   // keys unique: single owner pops
    }
    const int m1 = (cnt1 < CAND_CAP) ? cnt1 : CAND_CAP;
    u64 my1 = (lane < m1) ? cand[wave * 2 + 1][lane] : ~0ull;
#pragma unroll
    for (int r = 0; r < KNN; ++r) {
      u64 mm = wave_min_u64(my1);
      ni1_[r] = (int)(unsigned)(mm & 0xFFFFFFFFu);
      if (my1 == mm) my1 = ~0ull;
    }
  }

  // ---- attention (order-invariant). agg aliases q: each wave writes only
  // its own 2 rows, after reading its own q rows. ----
  const float lg = *log_gamma_p;
  attend_one(c4, q, k, v, lg, base, n0, qp0, ni0_, lane, agg);
  attend_one(c4, q, k, v, lg, base, n0 + 1, qp1, ni1_, lane, agg);
}

// ---------------------------------------------------------------------------
extern "C" void kernel_launch(void* const* d_in, const int* in_sizes, int n_in,
                              void* d_out, int out_size, void* d_ws, size_t ws_size,
                              hipStream_t stream) {
  const float* feats  = (const float*)d_in[0];
  const float* coords = (const float*)d_in[1];
  const float* Wq     = (const float*)d_in[2];
  const float* Wk     = (const float*)d_in[3];
  const float* Wv     = (const float*)d_in[4];
  const float* Wo     = (const float*)d_in[5];
  const float* lg     = (const float*)d_in[6];
  float* out = (float*)d_out;

  float* ws = (float*)d_ws;
  const size_t ROWS = (size_t)M_TOTAL * C_DIM;   // 2,097,152 floats
  float*  q   = ws;                               // 8 MB
  float*  k   = ws + ROWS;                        // 8 MB
  float*  v   = ws + 2 * ROWS;                    // 8 MB
  float4* c4  = (float4*)(ws + 3 * ROWS);         // 256 KB, 16B-aligned
  float*  WTq = ws + 3 * ROWS + 4 * (size_t)M_TOTAL;
  float*  WTk = WTq + C_DIM * C_DIM;
  float*  WTv = WTk + C_DIM * C_DIM;
  float*  WTo = WTv + C_DIM * C_DIM;              // total ws use: ~24.8 MB
  float*  agg = q;                                // reuse q's buffer

  prep_coords<<<M_TOTAL / 256, 256, 0, stream>>>(coords, c4);
  transpose_w<<<256, 256, 0, stream>>>(Wq, Wk, Wv, Wo, WTq, WTk, WTv, WTo);
  gemm_qkv<<<M_TOTAL / 64, 512, 0, stream>>>(feats, WTq, WTk, WTv, q, k, v);
  knn_attn<<<M_TOTAL / 8, 256, 0, stream>>>(c4, q, k, v, lg, agg);
  gemm_xwt<<<M_TOTAL / 64, 512, 0, stream>>>(agg, WTo, out);
}

// Round 9
// 229.789 us; speedup vs baseline: 1.4175x; 1.4175x over previous
//
#include <hip/hip_runtime.h>
#include <math.h>

#define C_DIM 128
#define KNN 8
#define NPTS 8192
#define M_TOTAL 16384   // B*N
#define CHUNK 1024      // points staged in LDS per iteration of the KNN scan
#define CAND_CAP 64     // per-query candidate buffer (expected use: 8-16)

typedef unsigned long long u64;

// ---------------------------------------------------------------------------
// Kernel 1: coords -> packed float4 {x, y, z, |p|^2} per point
// ---------------------------------------------------------------------------
__global__ __launch_bounds__(256) void prep_coords(
    const float* __restrict__ coords, float4* __restrict__ c4) {
  int g = blockIdx.x * 256 + threadIdx.x;
  if (g < M_TOTAL) {
    float x = coords[3 * g + 0];
    float y = coords[3 * g + 1];
    float z = coords[3 * g + 2];
    // same fma ordering as the scan's dot product so self-distance cancels
    // to exactly 0.0f
    float s = fmaf(x, x, fmaf(y, y, z * z));
    c4[g] = make_float4(x, y, z, s);
  }
}

// ---------------------------------------------------------------------------
// Kernel 2: transpose the four 128x128 weight matrices once: WT[c][o]=W[o][c]
// ---------------------------------------------------------------------------
__global__ __launch_bounds__(256) void transpose_w(
    const float* __restrict__ Wq, const float* __restrict__ Wk,
    const float* __restrict__ Wv, const float* __restrict__ Wo,
    float* __restrict__ Tq, float* __restrict__ Tk,
    float* __restrict__ Tv, float* __restrict__ To) {
  int g = blockIdx.x * 256 + threadIdx.x;
  int mat = g >> 14;          // 0..3
  int j = g & 16383;          // dest linear index: j = c*128 + o
  int c = j >> 7, o = j & 127;
  const float* src = (mat == 0) ? Wq : (mat == 1) ? Wk : (mat == 2) ? Wv : Wo;
  float* dst = (mat == 0) ? Tq : (mat == 1) ? Tk : (mat == 2) ? Tv : To;
  dst[j] = src[o * C_DIM + c];   // coalesced write, strided (L2-hit) read
}

// ---------------------------------------------------------------------------
__device__ __forceinline__ void stage_x64(
    float (*Xs)[132], const float* __restrict__ X, int row0, int t) {
  const float4* X4 = (const float4*)(X + (size_t)row0 * C_DIM);
  for (int i = t; i < 64 * 32; i += 256) {
    int r = i >> 5, c4i = i & 31;
    *(float4*)&Xs[r][c4i * 4] = X4[i];
  }
}

// ---------------------------------------------------------------------------
// Kernel 3a: fused q/k/v projection, interleaved in one c-loop.
// 256 threads, 64-row tiles (4 rows/thread W-reuse) — best measured config
// (R7: ~100us non-knn; R8's 512-thread halved rows/thread and regressed).
// ---------------------------------------------------------------------------
__global__ __launch_bounds__(256) void gemm_qkv(
    const float* __restrict__ X,
    const float* __restrict__ WTq, const float* __restrict__ WTk,
    const float* __restrict__ WTv,
    float* __restrict__ Yq, float* __restrict__ Yk, float* __restrict__ Yv) {
  __shared__ float Xs[64][132];
  const int t = threadIdx.x;
  const int row0 = blockIdx.x * 64;
  stage_x64(Xs, X, row0, t);
  __syncthreads();

  const int r0 = (t >> 4) * 4;
  const int o0 = (t & 15) * 8;

  float aq[4][8], ak[4][8], av[4][8];
#pragma unroll
  for (int i = 0; i < 4; ++i)
#pragma unroll
    for (int j = 0; j < 8; ++j) { aq[i][j] = 0.f; ak[i][j] = 0.f; av[i][j] = 0.f; }

  for (int c = 0; c < C_DIM; c += 4) {
    float xs[4][4];
#pragma unroll
    for (int i = 0; i < 4; ++i) {
      float4 xv = *(const float4*)&Xs[r0 + i][c];
      xs[i][0] = xv.x; xs[i][1] = xv.y; xs[i][2] = xv.z; xs[i][3] = xv.w;
    }
#pragma unroll
    for (int cc = 0; cc < 4; ++cc) {
      const size_t wrow = (size_t)(c + cc) * C_DIM + o0;
      float4 qa = *(const float4*)&WTq[wrow];
      float4 qb = *(const float4*)&WTq[wrow + 4];
      float4 ka = *(const float4*)&WTk[wrow];
      float4 kb = *(const float4*)&WTk[wrow + 4];
      float4 va = *(const float4*)&WTv[wrow];
      float4 vb = *(const float4*)&WTv[wrow + 4];
#pragma unroll
      for (int i = 0; i < 4; ++i) {
        float x = xs[i][cc];
        aq[i][0] = fmaf(x, qa.x, aq[i][0]); aq[i][1] = fmaf(x, qa.y, aq[i][1]);
        aq[i][2] = fmaf(x, qa.z, aq[i][2]); aq[i][3] = fmaf(x, qa.w, aq[i][3]);
        aq[i][4] = fmaf(x, qb.x, aq[i][4]); aq[i][5] = fmaf(x, qb.y, aq[i][5]);
        aq[i][6] = fmaf(x, qb.z, aq[i][6]); aq[i][7] = fmaf(x, qb.w, aq[i][7]);
        ak[i][0] = fmaf(x, ka.x, ak[i][0]); ak[i][1] = fmaf(x, ka.y, ak[i][1]);
        ak[i][2] = fmaf(x, ka.z, ak[i][2]); ak[i][3] = fmaf(x, ka.w, ak[i][3]);
        ak[i][4] = fmaf(x, kb.x, ak[i][4]); ak[i][5] = fmaf(x, kb.y, ak[i][5]);
        ak[i][6] = fmaf(x, kb.z, ak[i][6]); ak[i][7] = fmaf(x, kb.w, ak[i][7]);
        av[i][0] = fmaf(x, va.x, av[i][0]); av[i][1] = fmaf(x, va.y, av[i][1]);
        av[i][2] = fmaf(x, va.z, av[i][2]); av[i][3] = fmaf(x, va.w, av[i][3]);
        av[i][4] = fmaf(x, vb.x, av[i][4]); av[i][5] = fmaf(x, vb.y, av[i][5]);
        av[i][6] = fmaf(x, vb.z, av[i][6]); av[i][7] = fmaf(x, vb.w, av[i][7]);
      }
    }
  }

#pragma unroll
  for (int i = 0; i < 4; ++i) {
    const size_t yoff = (size_t)(row0 + r0 + i) * C_DIM + o0;
    *(float4*)&Yq[yoff] = make_float4(aq[i][0], aq[i][1], aq[i][2], aq[i][3]);
    *(float4*)&Yq[yoff + 4] = make_float4(aq[i][4], aq[i][5], aq[i][6], aq[i][7]);
    *(float4*)&Yk[yoff] = make_float4(ak[i][0], ak[i][1], ak[i][2], ak[i][3]);
    *(float4*)&Yk[yoff + 4] = make_float4(ak[i][4], ak[i][5], ak[i][6], ak[i][7]);
    *(float4*)&Yv[yoff] = make_float4(av[i][0], av[i][1], av[i][2], av[i][3]);
    *(float4*)&Yv[yoff + 4] = make_float4(av[i][4], av[i][5], av[i][6], av[i][7]);
  }
}

// ---------------------------------------------------------------------------
// Kernel 3b: single GEMM (output projection), 256 threads, 64-row tiles.
// ---------------------------------------------------------------------------
__global__ __launch_bounds__(256) void gemm_xwt(
    const float* __restrict__ X, const float* __restrict__ WT,
    float* __restrict__ Y) {
  __shared__ float Xs[64][132];
  const int t = threadIdx.x;
  const int row0 = blockIdx.x * 64;
  stage_x64(Xs, X, row0, t);
  __syncthreads();

  const int r0 = (t >> 4) * 4;
  const int o0 = (t & 15) * 8;

  float acc[4][8];
#pragma unroll
  for (int i = 0; i < 4; ++i)
#pragma unroll
    for (int j = 0; j < 8; ++j) acc[i][j] = 0.0f;

  for (int c = 0; c < C_DIM; c += 4) {
    float xs[4][4];
#pragma unroll
    for (int i = 0; i < 4; ++i) {
      float4 xv = *(const float4*)&Xs[r0 + i][c];
      xs[i][0] = xv.x; xs[i][1] = xv.y; xs[i][2] = xv.z; xs[i][3] = xv.w;
    }
#pragma unroll
    for (int cc = 0; cc < 4; ++cc) {
      const size_t wrow = (size_t)(c + cc) * C_DIM + o0;
      float4 wa = *(const float4*)&WT[wrow];
      float4 wb = *(const float4*)&WT[wrow + 4];
#pragma unroll
      for (int i = 0; i < 4; ++i) {
        float x = xs[i][cc];
        acc[i][0] = fmaf(x, wa.x, acc[i][0]); acc[i][1] = fmaf(x, wa.y, acc[i][1]);
        acc[i][2] = fmaf(x, wa.z, acc[i][2]); acc[i][3] = fmaf(x, wa.w, acc[i][3]);
        acc[i][4] = fmaf(x, wb.x, acc[i][4]); acc[i][5] = fmaf(x, wb.y, acc[i][5]);
        acc[i][6] = fmaf(x, wb.z, acc[i][6]); acc[i][7] = fmaf(x, wb.w, acc[i][7]);
      }
    }
  }

#pragma unroll
  for (int i = 0; i < 4; ++i) {
    float* yrow = Y + (size_t)(row0 + r0 + i) * C_DIM + o0;
    *(float4*)yrow = make_float4(acc[i][0], acc[i][1], acc[i][2], acc[i][3]);
    *(float4*)(yrow + 4) = make_float4(acc[i][4], acc[i][5], acc[i][6], acc[i][7]);
  }
}

// ---------------------------------------------------------------------------
// Kernel 4: fused KNN + attention, 2 queries/wave, CHEAP pass A.
// Pass A keeps only a per-lane TOP-2 (3 ops/pt vs 16-op top-8 bubble):
//   hi = max(m1, e); m1 = min(m1, e); m2 = min(m2, hi)
// tau = wave 8th-smallest of the 128 retained values. Subset order-statistic
// argument: retained R (128 vals) is a subset of all clamped d2, so
// 8th(R) >= global s8 -> filtering d2 <= tau in pass B keeps every true
// top-8 member. Looseness only if >=3 of true top-8 share a lane (rare):
// candidates ~10-16 << CAND_CAP=64. Pass B + final select are exact
// lex-(clamped d2, idx) = reference top_k semantics.
// ---------------------------------------------------------------------------
__device__ __forceinline__ u64 wave_min_u64(u64 x) {
#pragma unroll
  for (int off = 32; off > 0; off >>= 1) {
    u64 o = __shfl_xor(x, off, 64);
    x = (o < x) ? o : x;
  }
  return x;
}

// wave 8th-smallest over per-lane ascending pairs (m1 <= m2)
__device__ __forceinline__ float wave_8th_of_top2(float m1, float m2) {
  float u0 = m1, u1 = m2;
  float m = 0.0f;
#pragma unroll
  for (int r = 0; r < KNN; ++r) {
    m = u0;
#pragma unroll
    for (int off = 32; off > 0; off >>= 1) {
      float o = __shfl_xor(m, off, 64);
      m = fminf(m, o);
    }
    bool mine = (u0 == m);   // every lane holding m pops one element
    u0 = mine ? u1 : u0;
    u1 = mine ? INFINITY : u1;
  }
  return m;
}

__device__ __forceinline__ void attend_one(
    const float4* __restrict__ c4, const float* __restrict__ q,
    const float* __restrict__ k, const float* __restrict__ v,
    float lg, int base, int n, float4 qp, const int (&ni_)[KNN], int lane,
    float* __restrict__ agg) {
  const size_t qrow = (size_t)(base + n) * C_DIM;
  const float qv0 = q[qrow + lane];
  const float qv1 = q[qrow + lane + 64];

  float score[KNN];
#pragma unroll
  for (int j = 0; j < KNN; ++j) {
    const int mj = ni_[j];
    const size_t krow = (size_t)(base + mj) * C_DIM;
    float p = fmaf(qv1, k[krow + lane + 64], qv0 * k[krow + lane]);
#pragma unroll
    for (int off = 32; off > 0; off >>= 1) p += __shfl_xor(p, off, 64);
    // gamma from the diff-based safe norm (reference's second formula)
    const float4 pm = c4[base + mj];
    float dx = qp.x - pm.x, dy = qp.y - pm.y, dz = qp.z - pm.z;
    float d2p = fmaf(dx, dx, fmaf(dy, dy, dz * dz));
    float dist = d2p > 0.0f ? sqrtf(d2p) : 0.0f;
    float gw = expf(lg * dist);
    score[j] = (p / 11.313708498984761f) * gw;   // /sqrt(128) then *gamma
  }

  float mx = score[0];
#pragma unroll
  for (int j = 1; j < KNN; ++j) mx = fmaxf(mx, score[j]);
  float w[KNN]; float sum = 0.0f;
#pragma unroll
  for (int j = 0; j < KNN; ++j) { w[j] = expf(score[j] - mx); sum += w[j]; }
#pragma unroll
  for (int j = 0; j < KNN; ++j) w[j] = w[j] / sum;

  float a0 = 0.0f, a1 = 0.0f;
#pragma unroll
  for (int j = 0; j < KNN; ++j) {
    const size_t vrow = (size_t)(base + ni_[j]) * C_DIM;
    a0 = fmaf(w[j], v[vrow + lane], a0);
    a1 = fmaf(w[j], v[vrow + lane + 64], a1);
  }
  agg[qrow + lane] = a0;
  agg[qrow + lane + 64] = a1;
}

__global__ __launch_bounds__(256) void knn_attn(
    const float4* __restrict__ c4,
    const float* __restrict__ q, const float* __restrict__ k,
    const float* __restrict__ v, const float* __restrict__ log_gamma_p,
    float* __restrict__ agg) {
  __shared__ float4 pts[CHUNK];          // 16 KB
  __shared__ u64 cand[8][CAND_CAP];      // 4 KB, per-query candidate buffers

  const int t = threadIdx.x;
  const int wave = t >> 6;
  const int lane = t & 63;
  const int q0i = blockIdx.x * 8 + wave * 2;     // 8 queries/block; blocks
  const int b = q0i >> 13;                       // never straddle a batch
  const int n0 = q0i & (NPTS - 1);
  const int base = b * NPTS;

  const float4 qp0 = c4[base + n0];
  const float4 qp1 = c4[base + n0 + 1];
  const u64 lmask = (1ull << lane) - 1ull;

  // ---------------- pass A: per-lane top-2 only, branchless ---------------
  float m10 = INFINITY, m20 = INFINITY;   // query 0: best, 2nd best
  float m11 = INFINITY, m21 = INFINITY;   // query 1

  for (int ch = 0; ch < NPTS / CHUNK; ++ch) {
    __syncthreads();   // previous chunk fully consumed
    for (int i = t; i < CHUNK; i += 256) pts[i] = c4[base + ch * CHUNK + i];
    __syncthreads();

#pragma unroll
    for (int it = 0; it < CHUNK / 128; ++it) {   // 2 points x 2 queries
      const int ml = it * 128 + lane;
      const float4 pa = pts[ml];
      const float4 pb = pts[ml + 64];
      float dota0 = fmaf(qp0.x, pa.x, fmaf(qp0.y, pa.y, qp0.z * pa.z));
      float dotb0 = fmaf(qp0.x, pb.x, fmaf(qp0.y, pb.y, qp0.z * pb.z));
      float dota1 = fmaf(qp1.x, pa.x, fmaf(qp1.y, pa.y, qp1.z * pa.z));
      float dotb1 = fmaf(qp1.x, pb.x, fmaf(qp1.y, pb.y, qp1.z * pb.z));
      float d2a0 = fmaxf(qp0.w + pa.w - 2.0f * dota0, 0.0f);
      float d2b0 = fmaxf(qp0.w + pb.w - 2.0f * dotb0, 0.0f);
      float d2a1 = fmaxf(qp1.w + pa.w - 2.0f * dota1, 0.0f);
      float d2b1 = fmaxf(qp1.w + pb.w - 2.0f * dotb1, 0.0f);
      // top-2 update: 3 ops per point per query
      float h;
      h = fmaxf(m10, d2a0); m10 = fminf(m10, d2a0); m20 = fminf(m20, h);
      h = fmaxf(m10, d2b0); m10 = fminf(m10, d2b0); m20 = fminf(m20, h);
      h = fmaxf(m11, d2a1); m11 = fminf(m11, d2a1); m21 = fminf(m21, h);
      h = fmaxf(m11, d2b1); m11 = fminf(m11, d2b1); m21 = fminf(m21, h);
    }
  }

  const float tau0 = wave_8th_of_top2(m10, m20);
  const float tau1 = wave_8th_of_top2(m11, m21);

  // ---------------- pass B: collect candidates <= tau ---------------------
  int cnt0 = 0, cnt1 = 0;
  for (int ch = 0; ch < NPTS / CHUNK; ++ch) {
    __syncthreads();
    for (int i = t; i < CHUNK; i += 256) pts[i] = c4[base + ch * CHUNK + i];
    __syncthreads();

#pragma unroll
    for (int it = 0; it < CHUNK / 128; ++it) {
      const int ml = it * 128 + lane;
      const float4 pa = pts[ml];
      const float4 pb = pts[ml + 64];
      float dota0 = fmaf(qp0.x, pa.x, fmaf(qp0.y, pa.y, qp0.z * pa.z));
      float dotb0 = fmaf(qp0.x, pb.x, fmaf(qp0.y, pb.y, qp0.z * pb.z));
      float dota1 = fmaf(qp1.x, pa.x, fmaf(qp1.y, pa.y, qp1.z * pa.z));
      float dotb1 = fmaf(qp1.x, pb.x, fmaf(qp1.y, pb.y, qp1.z * pb.z));
      float d2a0 = fmaxf(qp0.w + pa.w - 2.0f * dota0, 0.0f);
      float d2b0 = fmaxf(qp0.w + pb.w - 2.0f * dotb0, 0.0f);
      float d2a1 = fmaxf(qp1.w + pa.w - 2.0f * dota1, 0.0f);
      float d2b1 = fmaxf(qp1.w + pb.w - 2.0f * dotb1, 0.0f);
      bool ga0 = d2a0 <= tau0, gb0 = d2b0 <= tau0;
      bool ga1 = d2a1 <= tau1, gb1 = d2b1 <= tau1;
      u64 ma0 = __ballot(ga0), mb0 = __ballot(gb0);
      u64 ma1 = __ballot(ga1), mb1 = __ballot(gb1);
      if (ma0 | mb0 | ma1 | mb1) {   // rarely-taken, wave-uniform branch
        const unsigned ia = (unsigned)(ch * CHUNK + ml);
        if (ga0) {
          int pos = cnt0 + (int)__popcll(ma0 & lmask);
          if (pos < CAND_CAP)
            cand[wave * 2][pos] = ((u64)__float_as_uint(d2a0) << 32) | ia;
        }
        cnt0 += (int)__popcll(ma0);
        if (gb0) {
          int pos = cnt0 + (int)__popcll(mb0 & lmask);
          if (pos < CAND_CAP)
            cand[wave * 2][pos] = ((u64)__float_as_uint(d2b0) << 32) | (ia + 64);
        }
        cnt0 += (int)__popcll(mb0);
        if (ga1) {
          int pos = cnt1 + (int)__popcll(ma1 & lmask);
          if (pos < CAND_CAP)
            cand[wave * 2 + 1][pos] = ((u64)__float_as_uint(d2a1) << 32) | ia;
        }
        cnt1 += (int)__popcll(ma1);
        if (gb1) {
          int pos = cnt1 + (int)__popcll(mb1 & lmask);
          if (pos < CAND_CAP)
            cand[wave * 2 + 1][pos] = ((u64)__float_as_uint(d2b1) << 32) | (ia + 64);
        }
        cnt1 += (int)__popcll(mb1);
      }
    }
  }

  // ------------- final exact top-8 per query (lex (d2, idx)) -------------
  int ni0_[KNN], ni1_[KNN];
  {
    const int m0 = (cnt0 < CAND_CAP) ? cnt0 : CAND_CAP;
    u64 my0 = (lane < m0) ? cand[wave * 2][lane] : ~0ull;
#pragma unroll
    for (int r = 0; r < KNN; ++r) {
      u64 mm = wave_min_u64(my0);
      ni0_[r] = (int)(unsigned)(mm & 0xFFFFFFFFu);
      if (my0 == mm) my0 = ~0ull;   // keys unique: single owner pops
    }
    const int m1 = (cnt1 < CAND_CAP) ? cnt1 : CAND_CAP;
    u64 my1 = (lane < m1) ? cand[wave * 2 + 1][lane] : ~0ull;
#pragma unroll
    for (int r = 0; r < KNN; ++r) {
      u64 mm = wave_min_u64(my1);
      ni1_[r] = (int)(unsigned)(mm & 0xFFFFFFFFu);
      if (my1 == mm) my1 = ~0ull;
    }
  }

  // ---- attention (order-invariant). agg aliases q: each wave writes only
  // its own 2 rows, after reading its own q rows. ----
  const float lg = *log_gamma_p;
  attend_one(c4, q, k, v, lg, base, n0, qp0, ni0_, lane, agg);
  attend_one(c4, q, k, v, lg, base, n0 + 1, qp1, ni1_, lane, agg);
}

// ---------------------------------------------------------------------------
extern "C" void kernel_launch(void* const* d_in, const int* in_sizes, int n_in,
                              void* d_out, int out_size, void* d_ws, size_t ws_size,
                              hipStream_t stream) {
  const float* feats  = (const float*)d_in[0];
  const float* coords = (const float*)d_in[1];
  const float* Wq     = (const float*)d_in[2];
  const float* Wk     = (const float*)d_in[3];
  const float* Wv     = (const float*)d_in[4];
  const float* Wo     = (const float*)d_in[5];
  const float* lg     = (const float*)d_in[6];
  float* out = (float*)d_out;

  float* ws = (float*)d_ws;
  const size_t ROWS = (size_t)M_TOTAL * C_DIM;   // 2,097,152 floats
  float*  q   = ws;                               // 8 MB
  float*  k   = ws + ROWS;                        // 8 MB
  float*  v   = ws + 2 * ROWS;                    // 8 MB
  float4* c4  = (float4*)(ws + 3 * ROWS);         // 256 KB, 16B-aligned
  float*  WTq = ws + 3 * ROWS + 4 * (size_t)M_TOTAL;
  float*  WTk = WTq + C_DIM * C_DIM;
  float*  WTv = WTk + C_DIM * C_DIM;
  float*  WTo = WTv + C_DIM * C_DIM;              // total ws use: ~24.8 MB
  float*  agg = q;                                // reuse q's buffer

  prep_coords<<<M_TOTAL / 256, 256, 0, stream>>>(coords, c4);
  transpose_w<<<256, 256, 0, stream>>>(Wq, Wk, Wv, Wo, WTq, WTk, WTv, WTo);
  gemm_qkv<<<M_TOTAL / 64, 256, 0, stream>>>(feats, WTq, WTk, WTv, q, k, v);
  knn_attn<<<M_TOTAL / 8, 256, 0, stream>>>(c4, q, k, v, lg, agg);
  gemm_xwt<<<M_TOTAL / 64, 256, 0, stream>>>(agg, WTo, out);
}